// Round 1
// baseline (1675.634 us; speedup 1.0000x reference)
//
#include <hip/hip_runtime.h>
#include <math.h>

// ---------------------------------------------------------------------------
// MultiModalGraphSAGE — fused fp32 pipeline.
//   h0 = relu(concat(sf, mf) @ enc_w + enc_b)                    [N,128]
//   agg0 = mean_neigh(h0)                                        [N,128]
//   h1 = relu(bn0(h0@ws0 + agg0@wn0 + b0))                       [N,256]
//   s1 = h1@ws1 ; t1 = h1@wn1  (aggregate AFTER matmul: linear)  [N,128]
//   h2 = relu(bn1(s1 + mean_neigh(t1) + b1))                     [N,128]
//   r  = relu(h0@rel_w[:128] + h2@rel_w[128:] + rel_b)           [N,128]
//   out = relu(r@cls_w1+cb1) @ cls_w2 + cb2                      [N,32]
// Workspace: h0(51.2MB) + bufA(51.2MB) + h1(102.4MB) + bufB(51.2MB)
//            + CSR ints (~4.4MB)  ≈ 260 MB
// ---------------------------------------------------------------------------

#define EPS 1e-5f

// ---------------- CSR build ----------------

__global__ void zero_int(int* __restrict__ p, int n) {
    int i = blockIdx.x * 256 + threadIdx.x;
    if (i < n) p[i] = 0;
}

__global__ void count_deg(const int* __restrict__ dst, int* __restrict__ deg, int e) {
    int i = blockIdx.x * 256 + threadIdx.x;
    if (i < e) atomicAdd(&deg[dst[i]], 1);
}

// single-block chunked Hillis-Steele exclusive scan: rowptr[0..n] from deg[0..n-1]
__global__ __launch_bounds__(1024) void scan_deg(const int* __restrict__ deg,
                                                 int* __restrict__ rowptr, int n) {
    __shared__ int buf[1024];
    __shared__ int carry;
    const int tid = threadIdx.x;
    if (tid == 0) carry = 0;
    __syncthreads();
    for (int base = 0; base < n; base += 1024) {
        int i = base + tid;
        int v = (i < n) ? deg[i] : 0;
        buf[tid] = v;
        __syncthreads();
        #pragma unroll 1
        for (int off = 1; off < 1024; off <<= 1) {
            int t = (tid >= off) ? buf[tid - off] : 0;
            __syncthreads();
            buf[tid] += t;
            __syncthreads();
        }
        int incl = buf[tid];
        int total = buf[1023];
        if (i < n) rowptr[i] = carry + incl - v;   // exclusive
        __syncthreads();
        if (tid == 0) carry += total;
        __syncthreads();
    }
    if (tid == 0) rowptr[n] = carry;
}

__global__ void copy_int(const int* __restrict__ a, int* __restrict__ b, int n) {
    int i = blockIdx.x * 256 + threadIdx.x;
    if (i < n) b[i] = a[i];
}

__global__ void fill_edges(const int* __restrict__ src, const int* __restrict__ dst,
                           int* __restrict__ cursor, int* __restrict__ eidx, int e) {
    int i = blockIdx.x * 256 + threadIdx.x;
    if (i < e) {
        int pos = atomicAdd(&cursor[dst[i]], 1);
        eidx[pos] = src[i];
    }
}

// ---------------- mean aggregation over CSR (D = 128, one wave per node) ----
// if addsrc != null: out = relu(bn(addsrc + mean + bias))  (sage1 combine)
__global__ __launch_bounds__(256)
void agg_mean128(const float* __restrict__ feat,
                 const int* __restrict__ rowptr, const int* __restrict__ eidx,
                 const float* __restrict__ addsrc, const float* __restrict__ bias,
                 const float* __restrict__ bng, const float* __restrict__ bnb,
                 const float* __restrict__ bnm, const float* __restrict__ bnv,
                 float* __restrict__ out, int n) {
    const int node = blockIdx.x * 4 + (threadIdx.x >> 6);
    if (node >= n) return;
    const int lane = threadIdx.x & 63;
    const int beg = rowptr[node], end = rowptr[node + 1];
    float sx = 0.f, sy = 0.f;
    for (int e = beg; e < end; ++e) {
        const float2 t = ((const float2*)(feat + (size_t)eidx[e] * 128))[lane];
        sx += t.x; sy += t.y;
    }
    const float inv = 1.0f / fmaxf((float)(end - beg), 1.0f);
    sx *= inv; sy *= inv;
    if (addsrc) {
        const int c = lane * 2;
        const float2 s = ((const float2*)(addsrc + (size_t)node * 128))[lane];
        float v0 = s.x + sx + bias[c];
        float v1 = s.y + sy + bias[c + 1];
        v0 = (v0 - bnm[c])     * (bng[c]     / sqrtf(bnv[c]     + EPS)) + bnb[c];
        v1 = (v1 - bnm[c + 1]) * (bng[c + 1] / sqrtf(bnv[c + 1] + EPS)) + bnb[c + 1];
        sx = fmaxf(v0, 0.f);
        sy = fmaxf(v1, 0.f);
    }
    ((float2*)(out + (size_t)node * 128))[lane] = make_float2(sx, sy);
}

// ---------------- fp32 GEMM: C = epilogue(A1@W1 + A2@W2) -------------------
// A row-major [M,K*], W row-major [K*,N]. 128x128 tile, BK=8, 8x8/thread.
// K1,K2 multiples of 8; N multiple of 4.
__global__ __launch_bounds__(256)
void gemm128(const float* __restrict__ A1, int K1, int lda1,
             const float* __restrict__ A2, int K2, int lda2,
             const float* __restrict__ W1, const float* __restrict__ W2,
             const float* __restrict__ bias,
             const float* __restrict__ bng, const float* __restrict__ bnb,
             const float* __restrict__ bnm, const float* __restrict__ bnv,
             int relu,
             float* __restrict__ C, int M, int N) {
    __shared__ float As[8][132];
    __shared__ float Bs[8][132];
    const int tid = threadIdx.x;
    const int bm = blockIdx.y * 128;
    const int bn = blockIdx.x * 128;
    const int a_row = tid >> 1;            // 0..127
    const int a_k   = (tid & 1) * 4;       // 0,4
    const int b_k   = tid >> 5;            // 0..7
    const int b_col = (tid & 31) * 4;      // 0..124
    const int m0 = (tid >> 4) * 8;         // 0..120
    const int n0 = (tid & 15) * 8;         // 0..120

    float acc[8][8];
    #pragma unroll
    for (int i = 0; i < 8; ++i)
        #pragma unroll
        for (int j = 0; j < 8; ++j) acc[i][j] = 0.f;

    const int K = K1 + K2;
    for (int kt = 0; kt < K; kt += 8) {
        const float* Ap; const float* Wp; int lda, kb;
        if (kt < K1) { Ap = A1; Wp = W1; lda = lda1; kb = kt; }
        else         { Ap = A2; Wp = W2; lda = lda2; kb = kt - K1; }

        float4 av = make_float4(0.f, 0.f, 0.f, 0.f);
        const int gr = bm + a_row;
        if (gr < M) av = *(const float4*)(Ap + (size_t)gr * lda + kb + a_k);
        As[a_k + 0][a_row] = av.x;
        As[a_k + 1][a_row] = av.y;
        As[a_k + 2][a_row] = av.z;
        As[a_k + 3][a_row] = av.w;

        float4 wv = make_float4(0.f, 0.f, 0.f, 0.f);
        const int gc = bn + b_col;
        if (gc + 4 <= N) wv = *(const float4*)(Wp + (size_t)(kb + b_k) * N + gc);
        *(float4*)&Bs[b_k][b_col] = wv;

        __syncthreads();
        #pragma unroll
        for (int k = 0; k < 8; ++k) {
            const float4 a0 = *(const float4*)&As[k][m0];
            const float4 a1 = *(const float4*)&As[k][m0 + 4];
            const float4 b0 = *(const float4*)&Bs[k][n0];
            const float4 b1 = *(const float4*)&Bs[k][n0 + 4];
            const float a[8] = {a0.x, a0.y, a0.z, a0.w, a1.x, a1.y, a1.z, a1.w};
            const float b[8] = {b0.x, b0.y, b0.z, b0.w, b1.x, b1.y, b1.z, b1.w};
            #pragma unroll
            for (int i = 0; i < 8; ++i)
                #pragma unroll
                for (int j = 0; j < 8; ++j) acc[i][j] += a[i] * b[j];
        }
        __syncthreads();
    }

    #pragma unroll
    for (int i = 0; i < 8; ++i) {
        const int r = bm + m0 + i;
        if (r >= M) continue;
        #pragma unroll
        for (int j = 0; j < 8; j += 4) {
            const int c = bn + n0 + j;
            if (c + 4 > N) continue;
            float v[4];
            #pragma unroll
            for (int q = 0; q < 4; ++q) {
                float x = acc[i][j + q];
                const int cc = c + q;
                if (bias) x += bias[cc];
                if (bng)  x = (x - bnm[cc]) * (bng[cc] / sqrtf(bnv[cc] + EPS)) + bnb[cc];
                if (relu) x = fmaxf(x, 0.f);
                v[q] = x;
            }
            *(float4*)(C + (size_t)r * N + c) =
                make_float4(v[0], v[1], v[2], v[3]);
        }
    }
}

// ---------------------------------------------------------------------------

extern "C" void kernel_launch(void* const* d_in, const int* in_sizes, int n_in,
                              void* d_out, int out_size, void* d_ws, size_t ws_size,
                              hipStream_t stream) {
    const float* sf    = (const float*)d_in[0];
    const float* mf    = (const float*)d_in[1];
    const int*   src   = (const int*)d_in[2];
    const int*   dst   = (const int*)d_in[3];
    const float* enc_w = (const float*)d_in[4];
    const float* enc_b = (const float*)d_in[5];
    const float* s0_ws = (const float*)d_in[6];
    const float* s0_wn = (const float*)d_in[7];
    const float* s0_b  = (const float*)d_in[8];
    const float* bn0_g = (const float*)d_in[9];
    const float* bn0_b = (const float*)d_in[10];
    const float* bn0_m = (const float*)d_in[11];
    const float* bn0_v = (const float*)d_in[12];
    const float* s1_ws = (const float*)d_in[13];
    const float* s1_wn = (const float*)d_in[14];
    const float* s1_b  = (const float*)d_in[15];
    const float* bn1_g = (const float*)d_in[16];
    const float* bn1_b = (const float*)d_in[17];
    const float* bn1_m = (const float*)d_in[18];
    const float* bn1_v = (const float*)d_in[19];
    const float* rel_w = (const float*)d_in[20];
    const float* rel_b = (const float*)d_in[21];
    const float* cw1   = (const float*)d_in[22];
    const float* cb1   = (const float*)d_in[23];
    const float* cw2   = (const float*)d_in[24];
    const float* cb2   = (const float*)d_in[25];
    float* out = (float*)d_out;

    const int nn = in_sizes[0] / 128;   // 100000
    const int ne = in_sizes[2];         // 800000

    // workspace layout
    float* h0   = (float*)d_ws;                       // [nn,128]
    float* bufA = h0   + (size_t)nn * 128;            // [nn,128]  agg0 -> t1 -> o1
    float* h1   = bufA + (size_t)nn * 128;            // [nn,256]  h1 -> h2 (first half)
    float* bufB = h1   + (size_t)nn * 256;            // [nn,128]  s1 -> r
    int* deg    = (int*)(bufB + (size_t)nn * 128);
    int* rowptr = deg + nn;
    int* cursor = rowptr + nn + 1;
    int* eidx   = cursor + nn;

    const dim3 blk(256);
    const int gM = (nn + 127) / 128;

    // --- CSR build (graph identical for both layers) ---
    zero_int  <<<dim3((nn + 255) / 256), blk, 0, stream>>>(deg, nn);
    count_deg <<<dim3((ne + 255) / 256), blk, 0, stream>>>(dst, deg, ne);
    scan_deg  <<<dim3(1), dim3(1024), 0, stream>>>(deg, rowptr, nn);
    copy_int  <<<dim3((nn + 255) / 256), blk, 0, stream>>>(rowptr, cursor, nn);
    fill_edges<<<dim3((ne + 255) / 256), blk, 0, stream>>>(src, dst, cursor, eidx, ne);

    // --- h0 = relu(concat(sf,mf) @ enc_w + enc_b) ---
    gemm128<<<dim3(1, gM), blk, 0, stream>>>(
        sf, 128, 128, mf, 384, 384, enc_w, enc_w + 128 * 128, enc_b,
        nullptr, nullptr, nullptr, nullptr, 1, h0, nn, 128);

    // --- agg0 = mean_neigh(h0) ---
    agg_mean128<<<dim3((nn + 3) / 4), blk, 0, stream>>>(
        h0, rowptr, eidx, nullptr, nullptr,
        nullptr, nullptr, nullptr, nullptr, bufA, nn);

    // --- h1 = relu(bn0(h0@ws0 + agg0@wn0 + b0)) ---
    gemm128<<<dim3(2, gM), blk, 0, stream>>>(
        h0, 128, 128, bufA, 128, 128, s0_ws, s0_wn, s0_b,
        bn0_g, bn0_b, bn0_m, bn0_v, 1, h1, nn, 256);

    // --- s1 = h1@ws1 -> bufB ; t1 = h1@wn1 -> bufA ---
    gemm128<<<dim3(1, gM), blk, 0, stream>>>(
        h1, 256, 256, nullptr, 0, 0, s1_ws, nullptr, nullptr,
        nullptr, nullptr, nullptr, nullptr, 0, bufB, nn, 128);
    gemm128<<<dim3(1, gM), blk, 0, stream>>>(
        h1, 256, 256, nullptr, 0, 0, s1_wn, nullptr, nullptr,
        nullptr, nullptr, nullptr, nullptr, 0, bufA, nn, 128);

    // --- h2 = relu(bn1(s1 + mean_neigh(t1) + b1)) -> h1 (reuse, [nn,128]) ---
    agg_mean128<<<dim3((nn + 3) / 4), blk, 0, stream>>>(
        bufA, rowptr, eidx, bufB, s1_b,
        bn1_g, bn1_b, bn1_m, bn1_v, h1, nn);

    // --- r = relu(h0@rel_w[:128] + h2@rel_w[128:] + rel_b) -> bufB ---
    gemm128<<<dim3(1, gM), blk, 0, stream>>>(
        h0, 128, 128, h1, 128, 128, rel_w, rel_w + 128 * 128, rel_b,
        nullptr, nullptr, nullptr, nullptr, 1, bufB, nn, 128);

    // --- o1 = relu(r@cls_w1 + cb1) -> bufA [nn,64] ---
    gemm128<<<dim3(1, gM), blk, 0, stream>>>(
        bufB, 128, 128, nullptr, 0, 0, cw1, nullptr, cb1,
        nullptr, nullptr, nullptr, nullptr, 1, bufA, nn, 64);

    // --- out = o1@cls_w2 + cb2 -> d_out [nn,32] ---
    gemm128<<<dim3(1, gM), blk, 0, stream>>>(
        bufA, 64, 64, nullptr, 0, 0, cw2, nullptr, cb2,
        nullptr, nullptr, nullptr, nullptr, 0, out, nn, 32);
}

// Round 2
// 1398.546 us; speedup vs baseline: 1.1981x; 1.1981x over previous
//
#include <hip/hip_runtime.h>
#include <math.h>

// ---------------------------------------------------------------------------
// MultiModalGraphSAGE — MFMA split-bf16 pipeline.
// fp32 value x is split x ~= hi + lo (two bf16); A@W computed as
// Ahi@Whi + Ahi@Wlo + Alo@Whi on matrix cores (fp32 accumulate).
// GEMMs are LDS-free: A frags read from fp32 activations and split in regs;
// B frags read from per-call transposed/split weights Wt[n][k] (bf16).
// ---------------------------------------------------------------------------

#define EPS 1e-5f

typedef __attribute__((ext_vector_type(8))) short bf16x8;
typedef __attribute__((ext_vector_type(4))) float f32x4;

__device__ inline unsigned short f2bf(float x) {
    unsigned u = __float_as_uint(x);
    u += 0x7fff + ((u >> 16) & 1);          // RNE to bf16
    return (unsigned short)(u >> 16);
}
__device__ inline float bf2f(unsigned short h) {
    return __uint_as_float(((unsigned)h) << 16);
}

// ---------------- CSR build ----------------

__global__ void zero_int(int* __restrict__ p, int n) {
    int i = blockIdx.x * 256 + threadIdx.x;
    if (i < n) p[i] = 0;
}

__global__ void count_deg(const int* __restrict__ dst, int* __restrict__ deg, int e) {
    int i = blockIdx.x * 256 + threadIdx.x;
    if (i < e) atomicAdd(&deg[dst[i]], 1);
}

__global__ __launch_bounds__(1024) void scan_deg(const int* __restrict__ deg,
                                                 int* __restrict__ rowptr, int n) {
    __shared__ int buf[1024];
    __shared__ int carry;
    const int tid = threadIdx.x;
    if (tid == 0) carry = 0;
    __syncthreads();
    for (int base = 0; base < n; base += 1024) {
        int i = base + tid;
        int v = (i < n) ? deg[i] : 0;
        buf[tid] = v;
        __syncthreads();
        #pragma unroll 1
        for (int off = 1; off < 1024; off <<= 1) {
            int t = (tid >= off) ? buf[tid - off] : 0;
            __syncthreads();
            buf[tid] += t;
            __syncthreads();
        }
        int incl = buf[tid];
        int total = buf[1023];
        if (i < n) rowptr[i] = carry + incl - v;   // exclusive
        __syncthreads();
        if (tid == 0) carry += total;
        __syncthreads();
    }
    if (tid == 0) rowptr[n] = carry;
}

__global__ void copy_int(const int* __restrict__ a, int* __restrict__ b, int n) {
    int i = blockIdx.x * 256 + threadIdx.x;
    if (i < n) b[i] = a[i];
}

__global__ void fill_edges(const int* __restrict__ src, const int* __restrict__ dst,
                           int* __restrict__ cursor, int* __restrict__ eidx, int e) {
    int i = blockIdx.x * 256 + threadIdx.x;
    if (i < e) {
        int pos = atomicAdd(&cursor[dst[i]], 1);
        eidx[pos] = src[i];
    }
}

// ---------------- weight prep: W[K][N] fp32 -> Wt hi/lo [N][ldt] bf16 -------

__global__ void prep_w(const float* __restrict__ W, int K, int N,
                       short* __restrict__ hi, short* __restrict__ lo,
                       int ldt, int koff) {
    int i = blockIdx.x * 256 + threadIdx.x;
    if (i >= K * N) return;
    int k = i / N, n = i - k * N;
    float x = W[i];
    unsigned short h = f2bf(x);
    unsigned short l = f2bf(x - bf2f(h));
    size_t o = (size_t)n * ldt + koff + k;
    hi[o] = (short)h;
    lo[o] = (short)l;
}

// ---------------- mean aggregation over CSR (D = 128, one wave per node) ----
// if addsrc != null: out = relu(bn(addsrc + mean + bias))  (sage1 combine)
__global__ __launch_bounds__(256)
void agg_mean128(const float* __restrict__ feat, int ldf,
                 const int* __restrict__ rowptr, const int* __restrict__ eidx,
                 const float* __restrict__ addsrc, int lds_,
                 const float* __restrict__ bias,
                 const float* __restrict__ bng, const float* __restrict__ bnb,
                 const float* __restrict__ bnm, const float* __restrict__ bnv,
                 float* __restrict__ out, int ldo, int n) {
    const int node = blockIdx.x * 4 + (threadIdx.x >> 6);
    if (node >= n) return;
    const int lane = threadIdx.x & 63;
    const int beg = rowptr[node], end = rowptr[node + 1];
    float sx = 0.f, sy = 0.f;
    for (int e = beg; e < end; ++e) {
        const float2 t = ((const float2*)(feat + (size_t)eidx[e] * ldf))[lane];
        sx += t.x; sy += t.y;
    }
    const float inv = 1.0f / fmaxf((float)(end - beg), 1.0f);
    sx *= inv; sy *= inv;
    if (addsrc) {
        const int c = lane * 2;
        const float2 s = ((const float2*)(addsrc + (size_t)node * lds_))[lane];
        float v0 = s.x + sx + bias[c];
        float v1 = s.y + sy + bias[c + 1];
        v0 = (v0 - bnm[c])     * (bng[c]     / sqrtf(bnv[c]     + EPS)) + bnb[c];
        v1 = (v1 - bnm[c + 1]) * (bng[c + 1] / sqrtf(bnv[c + 1] + EPS)) + bnb[c + 1];
        sx = fmaxf(v0, 0.f);
        sy = fmaxf(v1, 0.f);
    }
    ((float2*)(out + (size_t)node * ldo))[lane] = make_float2(sx, sy);
}

// ---------------- MFMA GEMM, LDS-free, split-bf16 ---------------------------
// Block: 256 thr = 4 waves stacked in M (128 rows). Each wave: 2 m-tiles x NT
// n-tiles of 16x16x32 MFMA. A: fp32 [M][lda] (dual source concat on K).
// B: Wt hi/lo bf16 [Nw][K] row-major (k contiguous). C: fp32 [M][ldc].
template<int NT>
__global__ __launch_bounds__(256)
void gemm_mfma(const float* __restrict__ A1, int K1, int lda1,
               const float* __restrict__ A2, int K2, int lda2,
               const short* __restrict__ Wt_hi, const short* __restrict__ Wt_lo,
               const float* __restrict__ bias,
               const float* __restrict__ bng, const float* __restrict__ bnb,
               const float* __restrict__ bnm, const float* __restrict__ bnv,
               int relu,
               float* __restrict__ C, int M, int ldc) {
    const int K = K1 + K2;                       // multiple of 32
    const int tid  = threadIdx.x;
    const int lane = tid & 63;
    const int wv   = tid >> 6;
    const int bm   = blockIdx.y * 128;
    const int col0 = blockIdx.x * (NT * 16);
    const int lrow = lane & 15;                  // A row in tile / C col in tile
    const int quad = lane >> 4;                  // 0..3
    const int kin  = quad * 8;                   // k offset within 32-chunk

    int ar[2];
    ar[0] = min(bm + wv * 32 + lrow,      M - 1);
    ar[1] = min(bm + wv * 32 + 16 + lrow, M - 1);

    f32x4 acc[2][NT];
    #pragma unroll
    for (int m = 0; m < 2; ++m)
        #pragma unroll
        for (int nt = 0; nt < NT; ++nt)
            acc[m][nt] = (f32x4){0.f, 0.f, 0.f, 0.f};

    for (int kb = 0; kb < K; kb += 32) {
        const float* __restrict__ Ap; int lda, kloc;
        if (kb < K1) { Ap = A1; lda = lda1; kloc = kb; }
        else         { Ap = A2; lda = lda2; kloc = kb - K1; }

        bf16x8 ah[2], al[2];
        #pragma unroll
        for (int m = 0; m < 2; ++m) {
            const float* p = Ap + (size_t)ar[m] * lda + kloc + kin;
            const float4 f0 = *(const float4*)p;
            const float4 f1 = *(const float4*)(p + 4);
            const float f[8] = {f0.x, f0.y, f0.z, f0.w, f1.x, f1.y, f1.z, f1.w};
            #pragma unroll
            for (int j = 0; j < 8; ++j) {
                const unsigned short hu = f2bf(f[j]);
                ah[m][j] = (short)hu;
                al[m][j] = (short)f2bf(f[j] - bf2f(hu));
            }
        }
        #pragma unroll
        for (int nt = 0; nt < NT; ++nt) {
            const size_t wo = (size_t)(col0 + nt * 16 + lrow) * K + kb + kin;
            const bf16x8 bh = *(const bf16x8*)(Wt_hi + wo);
            const bf16x8 bl = *(const bf16x8*)(Wt_lo + wo);
            #pragma unroll
            for (int m = 0; m < 2; ++m) {
                acc[m][nt] = __builtin_amdgcn_mfma_f32_16x16x32_bf16(ah[m], bh, acc[m][nt], 0, 0, 0);
                acc[m][nt] = __builtin_amdgcn_mfma_f32_16x16x32_bf16(ah[m], bl, acc[m][nt], 0, 0, 0);
                acc[m][nt] = __builtin_amdgcn_mfma_f32_16x16x32_bf16(al[m], bh, acc[m][nt], 0, 0, 0);
            }
        }
    }

    // epilogue: C/D layout col=lane&15, row=quad*4+reg
    #pragma unroll
    for (int nt = 0; nt < NT; ++nt) {
        const int gcol = col0 + nt * 16 + lrow;
        const float bsc = bias ? bias[gcol] : 0.f;
        float g = 1.f, bb = 0.f, mm = 0.f;
        if (bng) { g = bng[gcol] / sqrtf(bnv[gcol] + EPS); bb = bnb[gcol]; mm = bnm[gcol]; }
        #pragma unroll
        for (int m = 0; m < 2; ++m) {
            const int rbase = bm + wv * 32 + m * 16 + quad * 4;
            #pragma unroll
            for (int r = 0; r < 4; ++r) {
                const int grow = rbase + r;
                if (grow >= M) continue;
                float x = acc[m][nt][r] + bsc;
                if (bng) x = (x - mm) * g + bb;
                if (relu) x = fmaxf(x, 0.f);
                C[(size_t)grow * ldc + gcol] = x;
            }
        }
    }
}

// ---------------------------------------------------------------------------

extern "C" void kernel_launch(void* const* d_in, const int* in_sizes, int n_in,
                              void* d_out, int out_size, void* d_ws, size_t ws_size,
                              hipStream_t stream) {
    const float* sf    = (const float*)d_in[0];
    const float* mf    = (const float*)d_in[1];
    const int*   src   = (const int*)d_in[2];
    const int*   dst   = (const int*)d_in[3];
    const float* enc_w = (const float*)d_in[4];
    const float* enc_b = (const float*)d_in[5];
    const float* s0_ws = (const float*)d_in[6];
    const float* s0_wn = (const float*)d_in[7];
    const float* s0_b  = (const float*)d_in[8];
    const float* bn0_g = (const float*)d_in[9];
    const float* bn0_b = (const float*)d_in[10];
    const float* bn0_m = (const float*)d_in[11];
    const float* bn0_v = (const float*)d_in[12];
    const float* s1_ws = (const float*)d_in[13];
    const float* s1_wn = (const float*)d_in[14];
    const float* s1_b  = (const float*)d_in[15];
    const float* bn1_g = (const float*)d_in[16];
    const float* bn1_b = (const float*)d_in[17];
    const float* bn1_m = (const float*)d_in[18];
    const float* bn1_v = (const float*)d_in[19];
    const float* rel_w = (const float*)d_in[20];
    const float* rel_b = (const float*)d_in[21];
    const float* cw1   = (const float*)d_in[22];
    const float* cb1   = (const float*)d_in[23];
    const float* cw2   = (const float*)d_in[24];
    const float* cb2   = (const float*)d_in[25];
    float* out = (float*)d_out;

    const int nn = in_sizes[0] / 128;   // 100000
    const int ne = in_sizes[2];         // 800000

    // workspace layout (fp32 activations)
    float* h0 = (float*)d_ws;                    // [nn,128]  h0 (live to end)
    float* h1 = h0 + (size_t)nn * 128;           // [nn,256]  h1 -> h2 ([nn,128])
    float* st = h1 + (size_t)nn * 256;           // [nn,256]  agg0 -> s1|t1 -> r,o1
    int* deg    = (int*)(st + (size_t)nn * 256);
    int* rowptr = deg + nn;
    int* cursor = rowptr + nn + 1;
    int* eidx   = cursor + nn;
    // bf16 weight planes (hi, lo) — transposed [N][K]
    short* wts = (short*)(eidx + ne);
    short* wt_enc_h = wts;                 short* wt_enc_l = wt_enc_h + 65536;   // [128][512]
    short* wt_s0_h  = wt_enc_l + 65536;    short* wt_s0_l  = wt_s0_h  + 65536;   // [256][256]
    short* wt_st_h  = wt_s0_l  + 65536;    short* wt_st_l  = wt_st_h  + 65536;   // [256][256]
    short* wt_rel_h = wt_st_l  + 65536;    short* wt_rel_l = wt_rel_h + 32768;   // [128][256]
    short* wt_c1_h  = wt_rel_l + 32768;    short* wt_c1_l  = wt_c1_h  + 8192;    // [64][128]
    short* wt_c2_h  = wt_c1_l  + 8192;     short* wt_c2_l  = wt_c2_h  + 2048;    // [32][64]

    const dim3 blk(256);
    const int gM = (nn + 127) / 128;

    // --- CSR build ---
    zero_int  <<<dim3((nn + 255) / 256), blk, 0, stream>>>(deg, nn);
    count_deg <<<dim3((ne + 255) / 256), blk, 0, stream>>>(dst, deg, ne);
    scan_deg  <<<dim3(1), dim3(1024), 0, stream>>>(deg, rowptr, nn);
    copy_int  <<<dim3((nn + 255) / 256), blk, 0, stream>>>(rowptr, cursor, nn);
    fill_edges<<<dim3((ne + 255) / 256), blk, 0, stream>>>(src, dst, cursor, eidx, ne);

    // --- weight prep (tiny) ---
    prep_w<<<dim3(256), blk, 0, stream>>>(enc_w, 512, 128, wt_enc_h, wt_enc_l, 512, 0);
    prep_w<<<dim3(128), blk, 0, stream>>>(s0_ws, 128, 256, wt_s0_h, wt_s0_l, 256, 0);
    prep_w<<<dim3(128), blk, 0, stream>>>(s0_wn, 128, 256, wt_s0_h, wt_s0_l, 256, 128);
    prep_w<<<dim3(128), blk, 0, stream>>>(s1_ws, 256, 128, wt_st_h, wt_st_l, 256, 0);
    prep_w<<<dim3(128), blk, 0, stream>>>(s1_wn, 256, 128, wt_st_h + (size_t)128 * 256,
                                          wt_st_l + (size_t)128 * 256, 256, 0);
    prep_w<<<dim3(128), blk, 0, stream>>>(rel_w, 256, 128, wt_rel_h, wt_rel_l, 256, 0);
    prep_w<<<dim3(32),  blk, 0, stream>>>(cw1, 128, 64, wt_c1_h, wt_c1_l, 128, 0);
    prep_w<<<dim3(8),   blk, 0, stream>>>(cw2, 64, 32, wt_c2_h, wt_c2_l, 64, 0);

    // --- h0 = relu(concat(sf,mf) @ enc_w + enc_b) ---
    gemm_mfma<8><<<dim3(1, gM), blk, 0, stream>>>(
        sf, 128, 128, mf, 384, 384, wt_enc_h, wt_enc_l, enc_b,
        nullptr, nullptr, nullptr, nullptr, 1, h0, nn, 128);

    // --- agg0 = mean_neigh(h0) -> st (as [nn,128]) ---
    agg_mean128<<<dim3((nn + 3) / 4), blk, 0, stream>>>(
        h0, 128, rowptr, eidx, nullptr, 0, nullptr,
        nullptr, nullptr, nullptr, nullptr, st, 128, nn);

    // --- h1 = relu(bn0(h0@ws0 + agg0@wn0 + b0)) ---
    gemm_mfma<8><<<dim3(2, gM), blk, 0, stream>>>(
        h0, 128, 128, st, 128, 128, wt_s0_h, wt_s0_l, s0_b,
        bn0_g, bn0_b, bn0_m, bn0_v, 1, h1, nn, 256);

    // --- st = [s1 | t1] = h1 @ [ws1 | wn1] ---
    gemm_mfma<8><<<dim3(2, gM), blk, 0, stream>>>(
        h1, 256, 256, nullptr, 0, 0, wt_st_h, wt_st_l, nullptr,
        nullptr, nullptr, nullptr, nullptr, 0, st, nn, 256);

    // --- h2 = relu(bn1(s1 + mean_neigh(t1) + b1)) -> h1 region ([nn,128]) ---
    agg_mean128<<<dim3((nn + 3) / 4), blk, 0, stream>>>(
        st + 128, 256, rowptr, eidx, st, 256, s1_b,
        bn1_g, bn1_b, bn1_m, bn1_v, h1, 128, nn);

    // --- r = relu(h0@rel_w[:128] + h2@rel_w[128:] + rel_b) -> st ([nn,128]) ---
    gemm_mfma<8><<<dim3(1, gM), blk, 0, stream>>>(
        h0, 128, 128, h1, 128, 128, wt_rel_h, wt_rel_l, rel_b,
        nullptr, nullptr, nullptr, nullptr, 1, st, nn, 128);

    // --- o1 = relu(r@cls_w1 + cb1) -> st + nn*128 ([nn,64]) ---
    gemm_mfma<4><<<dim3(1, gM), blk, 0, stream>>>(
        st, 128, 128, nullptr, 0, 0, wt_c1_h, wt_c1_l, cb1,
        nullptr, nullptr, nullptr, nullptr, 1, st + (size_t)nn * 128, nn, 64);

    // --- out = o1@cls_w2 + cb2 -> d_out [nn,32] ---
    gemm_mfma<2><<<dim3(1, gM), blk, 0, stream>>>(
        st + (size_t)nn * 128, 64, 64, nullptr, 0, 0, wt_c2_h, wt_c2_l, cb2,
        nullptr, nullptr, nullptr, nullptr, 0, out, nn, 32);
}

// Round 3
// 1189.873 us; speedup vs baseline: 1.4082x; 1.1754x over previous
//
#include <hip/hip_runtime.h>
#include <math.h>

// ---------------------------------------------------------------------------
// MultiModalGraphSAGE — MFMA split-bf16 pipeline.
// fp32 value x is split x ~= hi + lo (two bf16); A@W computed as
// Ahi@Whi + Ahi@Wlo + Alo@Whi on matrix cores (fp32 accumulate).
// GEMMs are LDS-free: A frags read from fp32 activations and split in regs;
// B frags read from per-call transposed/split weights Wt[n][k] (bf16).
// CSR degree-scan is a 3-pass parallel scan (R2: was 219us single-block).
// ---------------------------------------------------------------------------

#define EPS 1e-5f

typedef __attribute__((ext_vector_type(8))) short bf16x8;
typedef __attribute__((ext_vector_type(4))) float f32x4;

__device__ inline unsigned short f2bf(float x) {
    unsigned u = __float_as_uint(x);
    u += 0x7fff + ((u >> 16) & 1);          // RNE to bf16
    return (unsigned short)(u >> 16);
}
__device__ inline float bf2f(unsigned short h) {
    return __uint_as_float(((unsigned)h) << 16);
}

// ---------------- CSR build ----------------

__global__ void zero_int(int* __restrict__ p, int n) {
    int i = blockIdx.x * 256 + threadIdx.x;
    if (i < n) p[i] = 0;
}

__global__ void count_deg(const int* __restrict__ dst, int* __restrict__ deg, int e) {
    int i = blockIdx.x * 256 + threadIdx.x;
    if (i < e) atomicAdd(&deg[dst[i]], 1);
}

// pass 1: per-block local exclusive scan (1024 elems/block) + block totals
__global__ __launch_bounds__(1024)
void scan_block(const int* __restrict__ deg, int* __restrict__ rowptr,
                int* __restrict__ part, int n) {
    __shared__ int buf[1024];
    const int tid = threadIdx.x;
    const int i = blockIdx.x * 1024 + tid;
    const int v = (i < n) ? deg[i] : 0;
    buf[tid] = v;
    __syncthreads();
    #pragma unroll 1
    for (int off = 1; off < 1024; off <<= 1) {
        int t = (tid >= off) ? buf[tid - off] : 0;
        __syncthreads();
        buf[tid] += t;
        __syncthreads();
    }
    if (i < n) rowptr[i] = buf[tid] - v;          // local exclusive
    if (tid == 1023) part[blockIdx.x] = buf[1023];
}

// pass 2: exclusive scan of block partials (nb <= 1024), part[nb] = total
__global__ __launch_bounds__(1024)
void scan_part(int* __restrict__ part, int nb) {
    __shared__ int buf[1024];
    const int tid = threadIdx.x;
    const int v = (tid < nb) ? part[tid] : 0;
    buf[tid] = v;
    __syncthreads();
    #pragma unroll 1
    for (int off = 1; off < 1024; off <<= 1) {
        int t = (tid >= off) ? buf[tid - off] : 0;
        __syncthreads();
        buf[tid] += t;
        __syncthreads();
    }
    if (tid < nb) part[tid] = buf[tid] - v;       // exclusive
    if (tid == 1023) part[nb] = buf[1023];        // grand total
}

// pass 3: add block offsets; also seed cursor[] (fused copy) and rowptr[n]
__global__ void scan_add(const int* __restrict__ part, int* __restrict__ rowptr,
                         int* __restrict__ cursor, int n, int nb) {
    int i = blockIdx.x * 256 + threadIdx.x;
    if (i < n) {
        int v = rowptr[i] + part[i >> 10];
        rowptr[i] = v;
        cursor[i] = v;
    }
    if (i == 0) rowptr[n] = part[nb];
}

__global__ void fill_edges(const int* __restrict__ src, const int* __restrict__ dst,
                           int* __restrict__ cursor, int* __restrict__ eidx, int e) {
    int i = blockIdx.x * 256 + threadIdx.x;
    if (i < e) {
        int pos = atomicAdd(&cursor[dst[i]], 1);
        eidx[pos] = src[i];
    }
}

// ---------------- weight prep: W[K][N] fp32 -> Wt hi/lo [N][ldt] bf16 -------

__global__ void prep_w(const float* __restrict__ W, int K, int N,
                       short* __restrict__ hi, short* __restrict__ lo,
                       int ldt, int koff) {
    int i = blockIdx.x * 256 + threadIdx.x;
    if (i >= K * N) return;
    int k = i / N, n = i - k * N;
    float x = W[i];
    unsigned short h = f2bf(x);
    unsigned short l = f2bf(x - bf2f(h));
    size_t o = (size_t)n * ldt + koff + k;
    hi[o] = (short)h;
    lo[o] = (short)l;
}

// ---------------- mean aggregation over CSR (D = 128, one wave per node) ----
// if addsrc != null: out = relu(bn(addsrc + mean + bias))  (sage1 combine)
__global__ __launch_bounds__(256)
void agg_mean128(const float* __restrict__ feat, int ldf,
                 const int* __restrict__ rowptr, const int* __restrict__ eidx,
                 const float* __restrict__ addsrc, int lds_,
                 const float* __restrict__ bias,
                 const float* __restrict__ bng, const float* __restrict__ bnb,
                 const float* __restrict__ bnm, const float* __restrict__ bnv,
                 float* __restrict__ out, int ldo, int n) {
    const int node = blockIdx.x * 4 + (threadIdx.x >> 6);
    if (node >= n) return;
    const int lane = threadIdx.x & 63;
    const int beg = rowptr[node], end = rowptr[node + 1];
    float sx = 0.f, sy = 0.f;
    for (int e = beg; e < end; ++e) {
        const float2 t = ((const float2*)(feat + (size_t)eidx[e] * ldf))[lane];
        sx += t.x; sy += t.y;
    }
    const float inv = 1.0f / fmaxf((float)(end - beg), 1.0f);
    sx *= inv; sy *= inv;
    if (addsrc) {
        const int c = lane * 2;
        const float2 s = ((const float2*)(addsrc + (size_t)node * lds_))[lane];
        float v0 = s.x + sx + bias[c];
        float v1 = s.y + sy + bias[c + 1];
        v0 = (v0 - bnm[c])     * (bng[c]     / sqrtf(bnv[c]     + EPS)) + bnb[c];
        v1 = (v1 - bnm[c + 1]) * (bng[c + 1] / sqrtf(bnv[c + 1] + EPS)) + bnb[c + 1];
        sx = fmaxf(v0, 0.f);
        sy = fmaxf(v1, 0.f);
    }
    ((float2*)(out + (size_t)node * ldo))[lane] = make_float2(sx, sy);
}

// ---------------- MFMA GEMM, LDS-free, split-bf16 ---------------------------
// Block: 256 thr = 4 waves stacked in M (128 rows). Each wave: 2 m-tiles x NT
// n-tiles of 16x16x32 MFMA. A: fp32 [M][lda] (dual source concat on K).
// B: Wt hi/lo bf16 [Nw][K] row-major (k contiguous). C: fp32 [M][ldc].
template<int NT>
__global__ __launch_bounds__(256)
void gemm_mfma(const float* __restrict__ A1, int K1, int lda1,
               const float* __restrict__ A2, int K2, int lda2,
               const short* __restrict__ Wt_hi, const short* __restrict__ Wt_lo,
               const float* __restrict__ bias,
               const float* __restrict__ bng, const float* __restrict__ bnb,
               const float* __restrict__ bnm, const float* __restrict__ bnv,
               int relu,
               float* __restrict__ C, int M, int ldc) {
    const int K = K1 + K2;                       // multiple of 32
    const int tid  = threadIdx.x;
    const int lane = tid & 63;
    const int wv   = tid >> 6;
    const int bm   = blockIdx.y * 128;
    const int col0 = blockIdx.x * (NT * 16);
    const int lrow = lane & 15;                  // A row in tile / C col in tile
    const int quad = lane >> 4;                  // 0..3
    const int kin  = quad * 8;                   // k offset within 32-chunk

    int ar[2];
    ar[0] = min(bm + wv * 32 + lrow,      M - 1);
    ar[1] = min(bm + wv * 32 + 16 + lrow, M - 1);

    f32x4 acc[2][NT];
    #pragma unroll
    for (int m = 0; m < 2; ++m)
        #pragma unroll
        for (int nt = 0; nt < NT; ++nt)
            acc[m][nt] = (f32x4){0.f, 0.f, 0.f, 0.f};

    for (int kb = 0; kb < K; kb += 32) {
        const float* __restrict__ Ap; int lda, kloc;
        if (kb < K1) { Ap = A1; lda = lda1; kloc = kb; }
        else         { Ap = A2; lda = lda2; kloc = kb - K1; }

        bf16x8 ah[2], al[2];
        #pragma unroll
        for (int m = 0; m < 2; ++m) {
            const float* p = Ap + (size_t)ar[m] * lda + kloc + kin;
            const float4 f0 = *(const float4*)p;
            const float4 f1 = *(const float4*)(p + 4);
            const float f[8] = {f0.x, f0.y, f0.z, f0.w, f1.x, f1.y, f1.z, f1.w};
            #pragma unroll
            for (int j = 0; j < 8; ++j) {
                const unsigned short hu = f2bf(f[j]);
                ah[m][j] = (short)hu;
                al[m][j] = (short)f2bf(f[j] - bf2f(hu));
            }
        }
        #pragma unroll
        for (int nt = 0; nt < NT; ++nt) {
            const size_t wo = (size_t)(col0 + nt * 16 + lrow) * K + kb + kin;
            const bf16x8 bh = *(const bf16x8*)(Wt_hi + wo);
            const bf16x8 bl = *(const bf16x8*)(Wt_lo + wo);
            #pragma unroll
            for (int m = 0; m < 2; ++m) {
                acc[m][nt] = __builtin_amdgcn_mfma_f32_16x16x32_bf16(ah[m], bh, acc[m][nt], 0, 0, 0);
                acc[m][nt] = __builtin_amdgcn_mfma_f32_16x16x32_bf16(ah[m], bl, acc[m][nt], 0, 0, 0);
                acc[m][nt] = __builtin_amdgcn_mfma_f32_16x16x32_bf16(al[m], bh, acc[m][nt], 0, 0, 0);
            }
        }
    }

    // epilogue: C/D layout col=lane&15, row=quad*4+reg
    #pragma unroll
    for (int nt = 0; nt < NT; ++nt) {
        const int gcol = col0 + nt * 16 + lrow;
        const float bsc = bias ? bias[gcol] : 0.f;
        float g = 1.f, bb = 0.f, mm = 0.f;
        if (bng) { g = bng[gcol] / sqrtf(bnv[gcol] + EPS); bb = bnb[gcol]; mm = bnm[gcol]; }
        #pragma unroll
        for (int m = 0; m < 2; ++m) {
            const int rbase = bm + wv * 32 + m * 16 + quad * 4;
            #pragma unroll
            for (int r = 0; r < 4; ++r) {
                const int grow = rbase + r;
                if (grow >= M) continue;
                float x = acc[m][nt][r] + bsc;
                if (bng) x = (x - mm) * g + bb;
                if (relu) x = fmaxf(x, 0.f);
                C[(size_t)grow * ldc + gcol] = x;
            }
        }
    }
}

// ---------------------------------------------------------------------------

extern "C" void kernel_launch(void* const* d_in, const int* in_sizes, int n_in,
                              void* d_out, int out_size, void* d_ws, size_t ws_size,
                              hipStream_t stream) {
    const float* sf    = (const float*)d_in[0];
    const float* mf    = (const float*)d_in[1];
    const int*   src   = (const int*)d_in[2];
    const int*   dst   = (const int*)d_in[3];
    const float* enc_w = (const float*)d_in[4];
    const float* enc_b = (const float*)d_in[5];
    const float* s0_ws = (const float*)d_in[6];
    const float* s0_wn = (const float*)d_in[7];
    const float* s0_b  = (const float*)d_in[8];
    const float* bn0_g = (const float*)d_in[9];
    const float* bn0_b = (const float*)d_in[10];
    const float* bn0_m = (const float*)d_in[11];
    const float* bn0_v = (const float*)d_in[12];
    const float* s1_ws = (const float*)d_in[13];
    const float* s1_wn = (const float*)d_in[14];
    const float* s1_b  = (const float*)d_in[15];
    const float* bn1_g = (const float*)d_in[16];
    const float* bn1_b = (const float*)d_in[17];
    const float* bn1_m = (const float*)d_in[18];
    const float* bn1_v = (const float*)d_in[19];
    const float* rel_w = (const float*)d_in[20];
    const float* rel_b = (const float*)d_in[21];
    const float* cw1   = (const float*)d_in[22];
    const float* cb1   = (const float*)d_in[23];
    const float* cw2   = (const float*)d_in[24];
    const float* cb2   = (const float*)d_in[25];
    float* out = (float*)d_out;

    const int nn = in_sizes[0] / 128;   // 100000
    const int ne = in_sizes[2];         // 800000
    const int nb = (nn + 1023) / 1024;  // scan blocks (98)

    // workspace layout (fp32 activations)
    float* h0 = (float*)d_ws;                    // [nn,128]  h0 (live to end)
    float* h1 = h0 + (size_t)nn * 128;           // [nn,256]  h1 -> h2 ([nn,128])
    float* st = h1 + (size_t)nn * 256;           // [nn,256]  agg0 -> s1|t1 -> r,o1
    int* deg    = (int*)(st + (size_t)nn * 256);
    int* rowptr = deg + nn;
    int* cursor = rowptr + nn + 1;
    int* part   = cursor + nn;                   // [nb+1]
    int* eidx   = part + nb + 1;
    // bf16 weight planes (hi, lo) — transposed [N][K]
    short* wts = (short*)(eidx + ne);
    short* wt_enc_h = wts;                 short* wt_enc_l = wt_enc_h + 65536;   // [128][512]
    short* wt_s0_h  = wt_enc_l + 65536;    short* wt_s0_l  = wt_s0_h  + 65536;   // [256][256]
    short* wt_st_h  = wt_s0_l  + 65536;    short* wt_st_l  = wt_st_h  + 65536;   // [256][256]
    short* wt_rel_h = wt_st_l  + 65536;    short* wt_rel_l = wt_rel_h + 32768;   // [128][256]
    short* wt_c1_h  = wt_rel_l + 32768;    short* wt_c1_l  = wt_c1_h  + 8192;    // [64][128]
    short* wt_c2_h  = wt_c1_l  + 8192;     short* wt_c2_l  = wt_c2_h  + 2048;    // [32][64]

    const dim3 blk(256);
    const int gM = (nn + 127) / 128;

    // --- CSR build (parallel scan) ---
    zero_int  <<<dim3((nn + 255) / 256), blk, 0, stream>>>(deg, nn);
    count_deg <<<dim3((ne + 255) / 256), blk, 0, stream>>>(dst, deg, ne);
    scan_block<<<dim3(nb), dim3(1024), 0, stream>>>(deg, rowptr, part, nn);
    scan_part <<<dim3(1),  dim3(1024), 0, stream>>>(part, nb);
    scan_add  <<<dim3((nn + 255) / 256), blk, 0, stream>>>(part, rowptr, cursor, nn, nb);
    fill_edges<<<dim3((ne + 255) / 256), blk, 0, stream>>>(src, dst, cursor, eidx, ne);

    // --- weight prep (tiny) ---
    prep_w<<<dim3(256), blk, 0, stream>>>(enc_w, 512, 128, wt_enc_h, wt_enc_l, 512, 0);
    prep_w<<<dim3(128), blk, 0, stream>>>(s0_ws, 128, 256, wt_s0_h, wt_s0_l, 256, 0);
    prep_w<<<dim3(128), blk, 0, stream>>>(s0_wn, 128, 256, wt_s0_h, wt_s0_l, 256, 128);
    prep_w<<<dim3(128), blk, 0, stream>>>(s1_ws, 256, 128, wt_st_h, wt_st_l, 256, 0);
    prep_w<<<dim3(128), blk, 0, stream>>>(s1_wn, 256, 128, wt_st_h + (size_t)128 * 256,
                                          wt_st_l + (size_t)128 * 256, 256, 0);
    prep_w<<<dim3(128), blk, 0, stream>>>(rel_w, 256, 128, wt_rel_h, wt_rel_l, 256, 0);
    prep_w<<<dim3(32),  blk, 0, stream>>>(cw1, 128, 64, wt_c1_h, wt_c1_l, 128, 0);
    prep_w<<<dim3(8),   blk, 0, stream>>>(cw2, 64, 32, wt_c2_h, wt_c2_l, 64, 0);

    // --- h0 = relu(concat(sf,mf) @ enc_w + enc_b) ---
    gemm_mfma<8><<<dim3(1, gM), blk, 0, stream>>>(
        sf, 128, 128, mf, 384, 384, wt_enc_h, wt_enc_l, enc_b,
        nullptr, nullptr, nullptr, nullptr, 1, h0, nn, 128);

    // --- agg0 = mean_neigh(h0) -> st (as [nn,128]) ---
    agg_mean128<<<dim3((nn + 3) / 4), blk, 0, stream>>>(
        h0, 128, rowptr, eidx, nullptr, 0, nullptr,
        nullptr, nullptr, nullptr, nullptr, st, 128, nn);

    // --- h1 = relu(bn0(h0@ws0 + agg0@wn0 + b0)) ---
    gemm_mfma<8><<<dim3(2, gM), blk, 0, stream>>>(
        h0, 128, 128, st, 128, 128, wt_s0_h, wt_s0_l, s0_b,
        bn0_g, bn0_b, bn0_m, bn0_v, 1, h1, nn, 256);

    // --- st = [s1 | t1] = h1 @ [ws1 | wn1] ---
    gemm_mfma<8><<<dim3(2, gM), blk, 0, stream>>>(
        h1, 256, 256, nullptr, 0, 0, wt_st_h, wt_st_l, nullptr,
        nullptr, nullptr, nullptr, nullptr, 0, st, nn, 256);

    // --- h2 = relu(bn1(s1 + mean_neigh(t1) + b1)) -> h1 region ([nn,128]) ---
    agg_mean128<<<dim3((nn + 3) / 4), blk, 0, stream>>>(
        st + 128, 256, rowptr, eidx, st, 256, s1_b,
        bn1_g, bn1_b, bn1_m, bn1_v, h1, 128, nn);

    // --- r = relu(h0@rel_w[:128] + h2@rel_w[128:] + rel_b) -> st ([nn,128]) ---
    gemm_mfma<8><<<dim3(1, gM), blk, 0, stream>>>(
        h0, 128, 128, h1, 128, 128, wt_rel_h, wt_rel_l, rel_b,
        nullptr, nullptr, nullptr, nullptr, 1, st, nn, 128);

    // --- o1 = relu(r@cls_w1 + cb1) -> st + nn*128 ([nn,64]) ---
    gemm_mfma<4><<<dim3(1, gM), blk, 0, stream>>>(
        st, 128, 128, nullptr, 0, 0, wt_c1_h, wt_c1_l, cb1,
        nullptr, nullptr, nullptr, nullptr, 1, st + (size_t)nn * 128, nn, 64);

    // --- out = o1@cls_w2 + cb2 -> d_out [nn,32] ---
    gemm_mfma<2><<<dim3(1, gM), blk, 0, stream>>>(
        st + (size_t)nn * 128, 64, 64, nullptr, 0, 0, wt_c2_h, wt_c2_l, cb2,
        nullptr, nullptr, nullptr, nullptr, 0, out, nn, 32);
}